// Round 4
// baseline (3936.022 us; speedup 1.0000x reference)
//
#include <hip/hip_runtime.h>
#include <hip/hip_bf16.h>
#include <hip/hip_cooperative_groups.h>

namespace cg = cooperative_groups;

#define DEV static __device__ __forceinline__

typedef short s16x8 __attribute__((ext_vector_type(8)));
typedef float f32x4 __attribute__((ext_vector_type(4)));
typedef unsigned short u16;

constexpr int Bn = 64, Pn = 196, ENCn = 2048, EMBn = 512, DECn = 512, ATTn = 512;
constexpr int VOCABn = 10000, Sn = 20;

DEV u16 f2bf(float x) {
  union { float f; unsigned u; } v; v.f = x;
  unsigned r = v.u + 0x7fffu + ((v.u >> 16) & 1u);
  return (u16)(r >> 16);
}
DEV float bf2f(u16 b) {
  union { unsigned u; float f; } v; v.u = ((unsigned)b) << 16;
  return v.f;
}
DEV float sigm(float x) { return 1.f / (1.f + __expf(-x)); }
DEV float tanh_fast(float x) {
  float e = __expf(2.f * x);
  return 1.f - 2.f / (e + 1.f);
}

DEV s16x8 ld8(const u16* p) { return *reinterpret_cast<const s16x8*>(p); }
DEV s16x8 ld8(const float* p) {
  s16x8 r;
#pragma unroll
  for (int j = 0; j < 8; j++) r[j] = (short)f2bf(p[j]);
  return r;
}
DEV f32x4 mfma(s16x8 a, s16x8 b, f32x4 c) {
  return __builtin_amdgcn_mfma_f32_16x16x32_bf16(a, b, c, 0, 0, 0);
}

#define GLOAD_LDS16(gsrc, ldst)                                                \
  __builtin_amdgcn_global_load_lds(                                            \
      (const __attribute__((address_space(1))) void*)(gsrc),                   \
      (__attribute__((address_space(3))) void*)(ldst), 16, 0, 0)

// ---------------- conversion f32 -> bf16, 8 elements/thread ----------------
__global__ void k_cvt8(const float* __restrict__ src, u16* __restrict__ dst, int n8) {
  int i = blockIdx.x * 256 + threadIdx.x;
  int stride = gridDim.x * 256;
  for (; i < n8; i += stride) {
    const float4* s = (const float4*)(src + (size_t)i * 8);
    float4 a = s[0], b = s[1];
    s16x8 o;
    o[0] = (short)f2bf(a.x); o[1] = (short)f2bf(a.y);
    o[2] = (short)f2bf(a.z); o[3] = (short)f2bf(a.w);
    o[4] = (short)f2bf(b.x); o[5] = (short)f2bf(b.y);
    o[6] = (short)f2bf(b.z); o[7] = (short)f2bf(b.w);
    *(s16x8*)(dst + (size_t)i * 8) = o;
  }
}

// ---------------- image_feat cvt fused with mean over P (7-way unrolled ILP) --
__global__ __launch_bounds__(256) void k_cvtfeat_avg(
    const float* __restrict__ feat, u16* __restrict__ featbf,
    float* __restrict__ avg) {
  int b = blockIdx.y, e = blockIdx.x * 256 + threadIdx.x;
  const float* p = feat + (size_t)b * Pn * ENCn + e;
  u16* q = featbf + (size_t)b * Pn * ENCn + e;
  float s = 0.f;
  for (int k0 = 0; k0 < Pn; k0 += 7) {   // 196 = 28 * 7
    float v[7];
#pragma unroll
    for (int j = 0; j < 7; j++) v[j] = p[(size_t)(k0 + j) * ENCn];
#pragma unroll
    for (int j = 0; j < 7; j++) {
      s += v[j];
      q[(size_t)(k0 + j) * ENCn] = f2bf(v[j]);
    }
  }
  avg[b * ENCn + e] = s * (1.0f / 196.0f);
}

// ---------------- generic skinny GEMM: C[64,N] = act(A[64,K] @ W[N,K]^T + b) ----
template<typename TA, typename TW, int ACT, int K>
__global__ __launch_bounds__(256) void k_lin64(
    const TA* __restrict__ A, const TW* __restrict__ W,
    const float* __restrict__ bias1,
    float* __restrict__ outF, size_t ldo, u16* __restrict__ outB) {
  int wid = threadIdx.x >> 6, lane = threadIdx.x & 63;
  int r = lane & 15, hi = lane >> 4;
  int n0 = blockIdx.x * 16;
  const TA* ap = A + (size_t)(wid * 16 + r) * K + hi * 8;
  const TW* wp = W + (size_t)(n0 + r) * K + hi * 8;
  f32x4 acc = {0.f, 0.f, 0.f, 0.f};
  for (int k = 0; k < K; k += 32) acc = mfma(ld8(ap + k), ld8(wp + k), acc);
  int col = n0 + r;
  float bb = bias1 ? bias1[col] : 0.f;
#pragma unroll
  for (int j = 0; j < 4; j++) {
    int row = wid * 16 + hi * 4 + j;
    float v = acc[j] + bb;
    if (ACT) v = fmaxf(v, 0.f);
    if (outF) outF[(size_t)row * ldo + col] = v;
    if (outB) outB[(size_t)row * DECn + col] = f2bf(v);
  }
}

// ---------------- enc_proj: 128x128 tile, BK=32, global_load_lds, bf16 out ----
__global__ __launch_bounds__(256) void k_encproj(
    const u16* __restrict__ Abf, const u16* __restrict__ Wbf,
    const float* __restrict__ bias, u16* __restrict__ out) {
  __shared__ u16 As[128][32];
  __shared__ u16 Bs[128][32];
  int tid = threadIdx.x;
  int wid = tid >> 6, lane = tid & 63, r = lane & 15, hi = lane >> 4;
  int wm = wid >> 1, wn = wid & 1;
  int m0 = blockIdx.y * 128, n0 = blockIdx.x * 128;
  int srow = tid >> 2, scol = (tid & 3) * 8;
  const u16* ga = Abf + (size_t)(m0 + srow) * ENCn + scol;
  const u16* gb = Wbf + (size_t)(n0 + srow) * ENCn + scol;
  u16* As1 = &As[0][0];
  u16* Bs1 = &Bs[0][0];
  f32x4 acc[4][4] = {};
  for (int k0 = 0; k0 < ENCn; k0 += 32) {
    GLOAD_LDS16(ga + k0,                      As1 + wid * 512);
    GLOAD_LDS16(ga + k0 + (size_t)64 * ENCn,  As1 + 2048 + wid * 512);
    GLOAD_LDS16(gb + k0,                      Bs1 + wid * 512);
    GLOAD_LDS16(gb + k0 + (size_t)64 * ENCn,  Bs1 + 2048 + wid * 512);
    __syncthreads();
    s16x8 af[4], bfr[4];
#pragma unroll
    for (int i = 0; i < 4; i++) af[i]  = *(const s16x8*)(As1 + (wm * 64 + i * 16 + r) * 32 + hi * 8);
#pragma unroll
    for (int j = 0; j < 4; j++) bfr[j] = *(const s16x8*)(Bs1 + (wn * 64 + j * 16 + r) * 32 + hi * 8);
#pragma unroll
    for (int i = 0; i < 4; i++)
#pragma unroll
      for (int j = 0; j < 4; j++)
        acc[i][j] = mfma(af[i], bfr[j], acc[i][j]);
    __syncthreads();
  }
#pragma unroll
  for (int i = 0; i < 4; i++)
#pragma unroll
    for (int j = 0; j < 4; j++) {
      int col = n0 + wn * 64 + j * 16 + r;
      float bb = bias[col];
#pragma unroll
      for (int q = 0; q < 4; q++) {
        int row = m0 + wm * 64 + i * 16 + hi * 4 + q;
        out[(size_t)row * 512 + col] = f2bf(acc[i][j][q] + bb);
      }
    }
}

// ---------------- persistent cooperative loop kernel --------------------------
// grid 256 blocks x 256 thr (1 block/CU). 5 grid.sync per step.
__global__ __launch_bounds__(256) void k_loop(
    const u16* __restrict__ encp, float* __restrict__ decp,
    const float* __restrict__ Vw, const float* __restrict__ Vb,
    float* __restrict__ e_s, const u16* __restrict__ featbf,
    u16* __restrict__ ctxbf, const float* __restrict__ embw,
    const int* __restrict__ caps, u16* __restrict__ hall,
    const u16* __restrict__ Wih, const u16* __restrict__ Whh,
    const float* __restrict__ bih, const float* __restrict__ bhh,
    float* __restrict__ cbuf, float* __restrict__ part,
    const u16* __restrict__ wdec, const float* __restrict__ wdecb) {
  cg::grid_group grid = cg::this_grid();
  int tid = threadIdx.x, wid = tid >> 6, lane = tid & 63;
  int r = lane & 15, hi = lane >> 4;
  int bx = blockIdx.x;
  __shared__ float red[256];
  __shared__ float sw[Pn];
  // constants preloaded for phase A
  float4 vv0 = *(const float4*)(Vw + lane * 8);
  float4 vv1 = *(const float4*)(Vw + lane * 8 + 4);
  float vb0 = Vb[0];

  for (int t = 0; t < Sn; t++) {
    // ---- Phase A: attention scores e_s[b][p] -------------------------------
    {
      int gw = bx * 4 + wid;        // 0..1023
      int b = gw >> 4, sub = gw & 15;
      const float* dp = decp + (size_t)b * ATTn + lane * 8;
      float4 dv0 = *(const float4*)dp;
      float4 dv1 = *(const float4*)(dp + 4);
      for (int p = sub; p < Pn; p += 16) {
        s16x8 ev = *(const s16x8*)(encp + (((size_t)(b * Pn + p)) << 9) + lane * 8);
        float s = 0.f;
        s += vv0.x * tanh_fast(bf2f((u16)ev[0]) + dv0.x);
        s += vv0.y * tanh_fast(bf2f((u16)ev[1]) + dv0.y);
        s += vv0.z * tanh_fast(bf2f((u16)ev[2]) + dv0.z);
        s += vv0.w * tanh_fast(bf2f((u16)ev[3]) + dv0.w);
        s += vv1.x * tanh_fast(bf2f((u16)ev[4]) + dv1.x);
        s += vv1.y * tanh_fast(bf2f((u16)ev[5]) + dv1.y);
        s += vv1.z * tanh_fast(bf2f((u16)ev[6]) + dv1.z);
        s += vv1.w * tanh_fast(bf2f((u16)ev[7]) + dv1.w);
        for (int m = 32; m; m >>= 1) s += __shfl_xor(s, m);
        if (lane == 0) e_s[b * Pn + p] = s + vb0;
      }
    }
    grid.sync();
    // ---- Phase B: softmax (per-block recompute) + ctx chunk -> bf16 --------
    {
      int b = bx >> 2, chunk = bx & 3;
      float ev = (tid < Pn) ? e_s[b * Pn + tid] : -3.0e38f;
      red[tid] = ev; __syncthreads();
      for (int s = 128; s > 0; s >>= 1) { if (tid < s) red[tid] = fmaxf(red[tid], red[tid + s]); __syncthreads(); }
      float m = red[0]; __syncthreads();
      float ex = (tid < Pn) ? __expf(ev - m) : 0.f;
      red[tid] = ex; __syncthreads();
      for (int s = 128; s > 0; s >>= 1) { if (tid < s) red[tid] += red[tid + s]; __syncthreads(); }
      float inv = 1.f / red[0];
      if (tid < Pn) sw[tid] = ex * inv;
      __syncthreads();
      int e0 = chunk * 512 + tid * 2;
      float ax = 0.f, ay = 0.f;
      const u16* fp = featbf + (size_t)b * Pn * ENCn + e0;
#pragma unroll 4
      for (int p = 0; p < Pn; p++) {
        float w = sw[p];
        unsigned v = *(const unsigned*)(fp + (size_t)p * ENCn);
        ax += w * bf2f((u16)(v & 0xffffu));
        ay += w * bf2f((u16)(v >> 16));
      }
      unsigned pk = (unsigned)f2bf(ax) | ((unsigned)f2bf(ay) << 16);
      *(unsigned*)(ctxbf + (size_t)b * ENCn + e0) = pk;
      __syncthreads();   // protect sw/red before next phase reuses LDS
    }
    grid.sync();
    // ---- Phase C: gates GEMM split into 2 K-slices -------------------------
    {
      int nb = bx & 127, sl = bx >> 7;
      int n0 = nb * 16;
      int brow = wid * 16 + r;
      f32x4 acc = {0.f, 0.f, 0.f, 0.f};
      if (sl == 0) {
        const u16* a = ctxbf + (size_t)brow * ENCn + hi * 8;
        const u16* w = Wih + (size_t)(n0 + r) * 2560 + hi * 8;
#pragma unroll 4
        for (int k = 0; k < 2048; k += 32) acc = mfma(ld8(a + k), ld8(w + k), acc);
      } else {
        int id = caps[brow * Sn + t];
        const float* a = embw + (size_t)id * EMBn + hi * 8;
        const u16* w = Wih + (size_t)(n0 + r) * 2560 + 2048 + hi * 8;
#pragma unroll 4
        for (int k = 0; k < 512; k += 32) acc = mfma(ld8(a + k), ld8(w + k), acc);
        const u16* a2 = hall + (size_t)t * Bn * DECn + (size_t)brow * DECn + hi * 8;
        const u16* w2 = Whh + (size_t)(n0 + r) * 512 + hi * 8;
#pragma unroll 4
        for (int k = 0; k < 512; k += 32) acc = mfma(ld8(a2 + k), ld8(w2 + k), acc);
      }
#pragma unroll
      for (int j = 0; j < 4; j++) {
        int row = wid * 16 + hi * 4 + j;
        part[((size_t)sl * 64 + row) * 2048 + n0 + r] = acc[j];
      }
    }
    grid.sync();
    // ---- Phase D: partial reduce + LSTM pointwise --------------------------
    if (tid < 128) {
      int idx = bx * 128 + tid;       // 256*128 = 32768 = 64*512
      int row = idx >> 9, d = idx & 511;
      float g[4];
#pragma unroll
      for (int gi = 0; gi < 4; gi++) {
        int col = gi * 512 + d;
        g[gi] = bih[col] + bhh[col]
              + part[((size_t)0 * 64 + row) * 2048 + col]
              + part[((size_t)1 * 64 + row) * 2048 + col];
      }
      size_t ci = (size_t)row * DECn + d;
      float cn = sigm(g[1]) * cbuf[ci] + sigm(g[0]) * tanh_fast(g[2]);
      float hn = sigm(g[3]) * tanh_fast(cn);
      cbuf[ci] = cn;
      hall[(size_t)(t + 1) * Bn * DECn + ci] = f2bf(hn);
    }
    grid.sync();
    // ---- Phase E: dec_proj for next step (32 active blocks) ----------------
    if (bx < 32) {
      int n0 = bx * 16;
      const u16* ap = hall + (size_t)(t + 1) * Bn * DECn + (size_t)(wid * 16 + r) * DECn + hi * 8;
      const u16* wp = wdec + (size_t)(n0 + r) * DECn + hi * 8;
      f32x4 acc = {0.f, 0.f, 0.f, 0.f};
#pragma unroll 4
      for (int k = 0; k < DECn; k += 32) acc = mfma(ld8(ap + k), ld8(wp + k), acc);
      float bb = wdecb[n0 + r];
#pragma unroll
      for (int j = 0; j < 4; j++) {
        int row = wid * 16 + hi * 4 + j;
        decp[(size_t)row * ATTn + n0 + r] = acc[j] + bb;
      }
    }
    grid.sync();
  }
}

// ---------------- deferred logits GEMM: [1280,10000] = Hall @ fcw^T + b -------
// A = hall rows 64..1343 (contiguous), tile 128x128, K=512.
__global__ __launch_bounds__(256) void k_logits(
    const u16* __restrict__ hA, const u16* __restrict__ Wbf,
    const float* __restrict__ bias, float* __restrict__ out) {
  __shared__ u16 As[128][32];
  __shared__ u16 Bs[128][32];
  int tid = threadIdx.x;
  int wid = tid >> 6, lane = tid & 63, r = lane & 15, hi = lane >> 4;
  int wm = wid >> 1, wn = wid & 1;
  int m0 = blockIdx.y * 128, n0 = blockIdx.x * 128;
  int srow = tid >> 2, scol = (tid & 3) * 8;
  const u16* ga = hA + (size_t)(m0 + srow) * 512 + scol;
  int br1 = n0 + srow;       if (br1 > VOCABn - 1) br1 = VOCABn - 1;
  int br2 = n0 + 64 + srow;  if (br2 > VOCABn - 1) br2 = VOCABn - 1;
  const u16* gb1 = Wbf + (size_t)br1 * 512 + scol;
  const u16* gb2 = Wbf + (size_t)br2 * 512 + scol;
  u16* As1 = &As[0][0];
  u16* Bs1 = &Bs[0][0];
  f32x4 acc[4][4] = {};
  for (int k0 = 0; k0 < 512; k0 += 32) {
    GLOAD_LDS16(ga + k0,                     As1 + wid * 512);
    GLOAD_LDS16(ga + k0 + (size_t)64 * 512,  As1 + 2048 + wid * 512);
    GLOAD_LDS16(gb1 + k0,                    Bs1 + wid * 512);
    GLOAD_LDS16(gb2 + k0,                    Bs1 + 2048 + wid * 512);
    __syncthreads();
    s16x8 af[4], bfr[4];
#pragma unroll
    for (int i = 0; i < 4; i++) af[i]  = *(const s16x8*)(As1 + (wm * 64 + i * 16 + r) * 32 + hi * 8);
#pragma unroll
    for (int j = 0; j < 4; j++) bfr[j] = *(const s16x8*)(Bs1 + (wn * 64 + j * 16 + r) * 32 + hi * 8);
#pragma unroll
    for (int i = 0; i < 4; i++)
#pragma unroll
      for (int j = 0; j < 4; j++)
        acc[i][j] = mfma(af[i], bfr[j], acc[i][j]);
    __syncthreads();
  }
#pragma unroll
  for (int i = 0; i < 4; i++)
#pragma unroll
    for (int j = 0; j < 4; j++) {
      int col = n0 + wn * 64 + j * 16 + r;
      if (col < VOCABn) {
        float bb = bias[col];
#pragma unroll
        for (int q = 0; q < 4; q++) {
          int row = m0 + wm * 64 + i * 16 + hi * 4 + q;   // row = t*64 + b
          int tt = row >> 6, b = row & 63;
          out[((size_t)b * Sn + tt) * VOCABn + col] = acc[i][j][q] + bb;
        }
      }
    }
}

// ============================================================================
extern "C" void kernel_launch(void* const* d_in, const int* in_sizes, int n_in,
                              void* d_out, int out_size, void* d_ws, size_t ws_size,
                              hipStream_t stream) {
  const float* image_feat = (const float*)d_in[0];
  const int*   captions   = (const int*)d_in[1];
  const float* wenc_w = (const float*)d_in[2];
  const float* wenc_b = (const float*)d_in[3];
  const float* wdec_w = (const float*)d_in[4];
  const float* wdec_b = (const float*)d_in[5];
  const float* V_w    = (const float*)d_in[6];
  const float* V_b    = (const float*)d_in[7];
  const float* embed_w = (const float*)d_in[8];
  const float* h0_w = (const float*)d_in[9];
  const float* h0_b = (const float*)d_in[10];
  const float* c0_w = (const float*)d_in[11];
  const float* c0_b = (const float*)d_in[12];
  const float* W_ih = (const float*)d_in[13];
  const float* b_ih = (const float*)d_in[14];
  const float* W_hh = (const float*)d_in[15];
  const float* b_hh = (const float*)d_in[16];
  const float* fc_w = (const float*)d_in[17];
  const float* fc_b = (const float*)d_in[18];
  float* out = (float*)d_out;

  char* w = (char*)d_ws;
  auto alloc = [&](size_t bytes) { void* p = (void*)w; w += (bytes + 255) & ~(size_t)255; return p; };
  u16* if_bf   = (u16*)alloc(sizeof(u16) * (size_t)Bn * Pn * ENCn);
  u16* wenc_bf = (u16*)alloc(sizeof(u16) * (size_t)ATTn * ENCn);
  u16* wdec_bf = (u16*)alloc(sizeof(u16) * (size_t)ATTn * DECn);
  u16* Wih_bf  = (u16*)alloc(sizeof(u16) * (size_t)2048 * 2560);
  u16* Whh_bf  = (u16*)alloc(sizeof(u16) * (size_t)2048 * 512);
  u16* fcw_bf  = (u16*)alloc(sizeof(u16) * (size_t)VOCABn * DECn);
  u16* hall    = (u16*)alloc(sizeof(u16) * (size_t)(Sn + 1) * Bn * DECn);
  u16* ctx_bf  = (u16*)alloc(sizeof(u16) * (size_t)Bn * ENCn);
  u16* encp    = (u16*)alloc(sizeof(u16) * (size_t)Bn * Pn * ATTn);
  float* avg   = (float*)alloc(sizeof(float) * (size_t)Bn * ENCn);
  float* decp  = (float*)alloc(sizeof(float) * (size_t)Bn * ATTn);
  float* e_s   = (float*)alloc(sizeof(float) * (size_t)Bn * Pn);
  float* cbuf  = (float*)alloc(sizeof(float) * (size_t)Bn * DECn);
  float* part  = (float*)alloc(sizeof(float) * (size_t)2 * Bn * 2048);

  auto cvt = [&](const float* s, u16* d, size_t n) {
    int n8 = (int)(n / 8);
    int blocks = (n8 + 255) / 256; if (blocks > 2048) blocks = 2048;
    k_cvt8<<<blocks, 256, 0, stream>>>(s, d, n8);
  };
  k_cvtfeat_avg<<<dim3(8, Bn), 256, 0, stream>>>(image_feat, if_bf, avg);
  cvt(wenc_w, wenc_bf, (size_t)ATTn * ENCn);
  cvt(wdec_w, wdec_bf, (size_t)ATTn * DECn);
  cvt(W_ih, Wih_bf, (size_t)2048 * 2560);
  cvt(W_hh, Whh_bf, (size_t)2048 * 512);
  cvt(fc_w, fcw_bf, (size_t)VOCABn * DECn);

  k_encproj<<<dim3(4, 98), 256, 0, stream>>>(if_bf, wenc_bf, wenc_b, encp);
  // h0 -> hall slot 0 (bf16), c0 -> cbuf (f32), decp0 = h0 @ wdec^T
  k_lin64<float, float, 1, 2048><<<32, 256, 0, stream>>>(avg, h0_w, h0_b, nullptr, 0, hall);
  k_lin64<float, float, 1, 2048><<<32, 256, 0, stream>>>(avg, c0_w, c0_b, cbuf, 512, nullptr);
  k_lin64<u16, u16, 0, 512><<<32, 256, 0, stream>>>(hall, wdec_bf, wdec_b, decp, 512, nullptr);

  // ---- persistent cooperative loop (all 20 steps, 5 grid.syncs each) ----
  {
    void* kargs[] = {
      (void*)&encp, (void*)&decp, (void*)&V_w, (void*)&V_b, (void*)&e_s,
      (void*)&if_bf, (void*)&ctx_bf, (void*)&embed_w, (void*)&captions,
      (void*)&hall, (void*)&Wih_bf, (void*)&Whh_bf, (void*)&b_ih,
      (void*)&b_hh, (void*)&cbuf, (void*)&part, (void*)&wdec_bf,
      (void*)&wdec_b
    };
    hipLaunchCooperativeKernel((const void*)k_loop, dim3(256), dim3(256),
                               kargs, 0, stream);
  }

  // ---- deferred logits for all steps: [1280,10000] GEMM ----
  k_logits<<<dim3(79, 10), 256, 0, stream>>>(hall + (size_t)Bn * DECn, fcw_bf, fc_b, out);
}

// Round 5
// 2025.933 us; speedup vs baseline: 1.9428x; 1.9428x over previous
//
#include <hip/hip_runtime.h>
#include <hip/hip_bf16.h>

#define DEV static __device__ __forceinline__

typedef short s16x8 __attribute__((ext_vector_type(8)));
typedef float f32x4 __attribute__((ext_vector_type(4)));
typedef unsigned short u16;

constexpr int Bn = 64, Pn = 196, ENCn = 2048, EMBn = 512, DECn = 512, ATTn = 512;
constexpr int VOCABn = 10000, Sn = 20;

DEV u16 f2bf(float x) {
  union { float f; unsigned u; } v; v.f = x;
  unsigned r = v.u + 0x7fffu + ((v.u >> 16) & 1u);
  return (u16)(r >> 16);
}
DEV float bf2f(u16 b) {
  union { unsigned u; float f; } v; v.u = ((unsigned)b) << 16;
  return v.f;
}
DEV float sigm(float x) { return 1.f / (1.f + __expf(-x)); }
DEV float tanh_fast(float x) {
  float e = __expf(2.f * x);
  return 1.f - 2.f / (e + 1.f);
}

DEV s16x8 ld8(const u16* p) { return *reinterpret_cast<const s16x8*>(p); }
DEV s16x8 ld8(const float* p) {
  s16x8 r;
#pragma unroll
  for (int j = 0; j < 8; j++) r[j] = (short)f2bf(p[j]);
  return r;
}
DEV f32x4 mfma(s16x8 a, s16x8 b, f32x4 c) {
  return __builtin_amdgcn_mfma_f32_16x16x32_bf16(a, b, c, 0, 0, 0);
}

#define GLOAD_LDS16(gsrc, ldst)                                                \
  __builtin_amdgcn_global_load_lds(                                            \
      (const __attribute__((address_space(1))) void*)(gsrc),                   \
      (__attribute__((address_space(3))) void*)(ldst), 16, 0, 0)

// ---------------- all weight conversions f32 -> bf16 in ONE launch ------------
__global__ void k_cvt_all(const float* __restrict__ s0, u16* __restrict__ d0,
                          const float* __restrict__ s1, u16* __restrict__ d1,
                          const float* __restrict__ s2, u16* __restrict__ d2,
                          const float* __restrict__ s3, u16* __restrict__ d3,
                          const float* __restrict__ s4, u16* __restrict__ d4) {
  int gid = blockIdx.x * 256 + threadIdx.x, stride = gridDim.x * 256;
  auto run = [&](const float* __restrict__ s, u16* __restrict__ d, int n8) {
    for (int i = gid; i < n8; i += stride) {
      const float4* sp = (const float4*)(s + (size_t)i * 8);
      float4 a = sp[0], b = sp[1];
      s16x8 o;
      o[0] = (short)f2bf(a.x); o[1] = (short)f2bf(a.y);
      o[2] = (short)f2bf(a.z); o[3] = (short)f2bf(a.w);
      o[4] = (short)f2bf(b.x); o[5] = (short)f2bf(b.y);
      o[6] = (short)f2bf(b.z); o[7] = (short)f2bf(b.w);
      *(s16x8*)(d + (size_t)i * 8) = o;
    }
  };
  run(s0, d0, 131072);   // wenc 512*2048
  run(s1, d1, 32768);    // wdec 512*512
  run(s2, d2, 655360);   // W_ih 2048*2560
  run(s3, d3, 131072);   // W_hh 2048*512
  run(s4, d4, 640000);   // fc_w 10000*512
}

// ---------------- image_feat cvt + mean, row-major float4 ---------------------
// grid (2, 64): block covers 1024 enc dims of one b; thread owns 4 dims.
__global__ __launch_bounds__(256) void k_cvtfeat_avg(
    const float* __restrict__ feat, u16* __restrict__ featbf,
    float* __restrict__ avg) {
  int b = blockIdx.y;
  int dim = blockIdx.x * 1024 + threadIdx.x * 4;
  const float* p = feat + (size_t)b * Pn * ENCn + dim;
  u16* q = featbf + (size_t)b * Pn * ENCn + dim;
  float sx = 0.f, sy = 0.f, sz = 0.f, sw = 0.f;
#pragma unroll 2
  for (int k = 0; k < Pn; k++) {
    float4 v = *(const float4*)(p + (size_t)k * ENCn);
    sx += v.x; sy += v.y; sz += v.z; sw += v.w;
    ushort4 o = { f2bf(v.x), f2bf(v.y), f2bf(v.z), f2bf(v.w) };
    *(ushort4*)(q + (size_t)k * ENCn) = o;
  }
  float4 a = { sx * (1.f/196.f), sy * (1.f/196.f), sz * (1.f/196.f), sw * (1.f/196.f) };
  *(float4*)(avg + (size_t)b * ENCn + dim) = a;
}

// ---------------- h0 + c0 in one launch (64 blocks) ---------------------------
__global__ __launch_bounds__(256) void k_h0c0(
    const float* __restrict__ avg,
    const float* __restrict__ h0w, const float* __restrict__ h0b,
    const float* __restrict__ c0w, const float* __restrict__ c0b,
    u16* __restrict__ h0out, float* __restrict__ c0out) {
  int wid = threadIdx.x >> 6, lane = threadIdx.x & 63;
  int r = lane & 15, hi = lane >> 4;
  bool isC = blockIdx.x >= 32;
  int n0 = ((int)blockIdx.x & 31) * 16;
  const float* W = (isC ? c0w : h0w) + (size_t)(n0 + r) * ENCn + hi * 8;
  const float* ap = avg + (size_t)(wid * 16 + r) * ENCn + hi * 8;
  f32x4 acc = {0.f, 0.f, 0.f, 0.f};
  for (int k = 0; k < ENCn; k += 32) acc = mfma(ld8(ap + k), ld8(W + k), acc);
  int col = n0 + r;
  float bb = (isC ? c0b : h0b)[col];
#pragma unroll
  for (int j = 0; j < 4; j++) {
    int row = wid * 16 + hi * 4 + j;
    float v = fmaxf(acc[j] + bb, 0.f);
    if (isC) c0out[(size_t)row * DECn + col] = v;
    else     h0out[(size_t)row * DECn + col] = f2bf(v);
  }
}

// ---------------- generic skinny GEMM (used once for decp0) -------------------
template<typename TA, typename TW, int K>
__global__ __launch_bounds__(256) void k_lin64(
    const TA* __restrict__ A, const TW* __restrict__ W,
    const float* __restrict__ bias1, float* __restrict__ outF, size_t ldo) {
  int wid = threadIdx.x >> 6, lane = threadIdx.x & 63;
  int r = lane & 15, hi = lane >> 4;
  int n0 = blockIdx.x * 16;
  const TA* ap = A + (size_t)(wid * 16 + r) * K + hi * 8;
  const TW* wp = W + (size_t)(n0 + r) * K + hi * 8;
  f32x4 acc = {0.f, 0.f, 0.f, 0.f};
  for (int k = 0; k < K; k += 32) acc = mfma(ld8(ap + k), ld8(wp + k), acc);
  int col = n0 + r;
  float bb = bias1[col];
#pragma unroll
  for (int j = 0; j < 4; j++) {
    int row = wid * 16 + hi * 4 + j;
    outF[(size_t)row * ldo + col] = acc[j] + bb;
  }
}

// ---------------- enc_proj: 128x128 tile, BK=32, global_load_lds, bf16 out ----
__global__ __launch_bounds__(256) void k_encproj(
    const u16* __restrict__ Abf, const u16* __restrict__ Wbf,
    const float* __restrict__ bias, u16* __restrict__ out) {
  __shared__ u16 As[128][32];
  __shared__ u16 Bs[128][32];
  int tid = threadIdx.x;
  int wid = tid >> 6, lane = tid & 63, r = lane & 15, hi = lane >> 4;
  int wm = wid >> 1, wn = wid & 1;
  int m0 = blockIdx.y * 128, n0 = blockIdx.x * 128;
  int srow = tid >> 2, scol = (tid & 3) * 8;
  const u16* ga = Abf + (size_t)(m0 + srow) * ENCn + scol;
  const u16* gb = Wbf + (size_t)(n0 + srow) * ENCn + scol;
  u16* As1 = &As[0][0];
  u16* Bs1 = &Bs[0][0];
  f32x4 acc[4][4] = {};
  for (int k0 = 0; k0 < ENCn; k0 += 32) {
    GLOAD_LDS16(ga + k0,                      As1 + wid * 512);
    GLOAD_LDS16(ga + k0 + (size_t)64 * ENCn,  As1 + 2048 + wid * 512);
    GLOAD_LDS16(gb + k0,                      Bs1 + wid * 512);
    GLOAD_LDS16(gb + k0 + (size_t)64 * ENCn,  Bs1 + 2048 + wid * 512);
    __syncthreads();
    s16x8 af[4], bfr[4];
#pragma unroll
    for (int i = 0; i < 4; i++) af[i]  = *(const s16x8*)(As1 + (wm * 64 + i * 16 + r) * 32 + hi * 8);
#pragma unroll
    for (int j = 0; j < 4; j++) bfr[j] = *(const s16x8*)(Bs1 + (wn * 64 + j * 16 + r) * 32 + hi * 8);
#pragma unroll
    for (int i = 0; i < 4; i++)
#pragma unroll
      for (int j = 0; j < 4; j++)
        acc[i][j] = mfma(af[i], bfr[j], acc[i][j]);
    __syncthreads();
  }
#pragma unroll
  for (int i = 0; i < 4; i++)
#pragma unroll
    for (int j = 0; j < 4; j++) {
      int col = n0 + wn * 64 + j * 16 + r;
      float bb = bias[col];
#pragma unroll
      for (int q = 0; q < 4; q++) {
        int row = m0 + wm * 64 + i * 16 + hi * 4 + q;
        out[(size_t)row * 512 + col] = f2bf(acc[i][j][q] + bb);
      }
    }
}

// ---------------- fused attention: e (redundant per chunk) + softmax + ctx ----
// grid (4, 64): (chunk of 512 enc dims, b). 256 thr = 4 waves.
__global__ __launch_bounds__(256) void k_attn_ctx(
    const u16* __restrict__ encp, const float* __restrict__ decp,
    const float* __restrict__ Vw, const float* __restrict__ Vb,
    const u16* __restrict__ featbf, u16* __restrict__ ctxbf) {
  __shared__ float e_lds[Pn];
  __shared__ float red[256];
  int b = blockIdx.y, chunk = blockIdx.x;
  int tid = threadIdx.x, wid = tid >> 6, lane = tid & 63;
  // per-lane constants (dims lane*8 .. lane*8+7)
  const float* dp = decp + (size_t)b * ATTn + lane * 8;
  float4 dv0 = *(const float4*)dp, dv1 = *(const float4*)(dp + 4);
  float4 vv0 = *(const float4*)(Vw + lane * 8), vv1 = *(const float4*)(Vw + lane * 8 + 4);
  float vb0 = Vb[0];
  // ---- e[b,p] for all p (waves split p) ----
  for (int p = wid; p < Pn; p += 4) {
    s16x8 ev = *(const s16x8*)(encp + (((size_t)(b * Pn + p)) << 9) + lane * 8);
    float s = 0.f;
    s += vv0.x * tanh_fast(bf2f((u16)ev[0]) + dv0.x);
    s += vv0.y * tanh_fast(bf2f((u16)ev[1]) + dv0.y);
    s += vv0.z * tanh_fast(bf2f((u16)ev[2]) + dv0.z);
    s += vv0.w * tanh_fast(bf2f((u16)ev[3]) + dv0.w);
    s += vv1.x * tanh_fast(bf2f((u16)ev[4]) + dv1.x);
    s += vv1.y * tanh_fast(bf2f((u16)ev[5]) + dv1.y);
    s += vv1.z * tanh_fast(bf2f((u16)ev[6]) + dv1.z);
    s += vv1.w * tanh_fast(bf2f((u16)ev[7]) + dv1.w);
    for (int m = 32; m; m >>= 1) s += __shfl_xor(s, m);
    if (lane == 0) e_lds[p] = s + vb0;
  }
  __syncthreads();
  // ---- softmax over 196 (block-wide) ----
  float ev = (tid < Pn) ? e_lds[tid] : -3.0e38f;
  red[tid] = ev; __syncthreads();
  for (int s = 128; s > 0; s >>= 1) { if (tid < s) red[tid] = fmaxf(red[tid], red[tid + s]); __syncthreads(); }
  float m = red[0]; __syncthreads();
  float ex = (tid < Pn) ? __expf(ev - m) : 0.f;
  red[tid] = ex; __syncthreads();
  for (int s = 128; s > 0; s >>= 1) { if (tid < s) red[tid] += red[tid + s]; __syncthreads(); }
  float inv = 1.f / red[0];
  __syncthreads();
  if (tid < Pn) e_lds[tid] = ex * inv;   // weights, in place
  __syncthreads();
  // ---- ctx chunk: 512 dims, 2 per thread ----
  int e0 = chunk * 512 + tid * 2;
  float ax = 0.f, ay = 0.f;
  const u16* fp = featbf + (size_t)b * Pn * ENCn + e0;
#pragma unroll 4
  for (int p = 0; p < Pn; p++) {
    float w = e_lds[p];
    unsigned v = *(const unsigned*)(fp + (size_t)p * ENCn);
    ax += w * bf2f((u16)(v & 0xffffu));
    ay += w * bf2f((u16)(v >> 16));
  }
  unsigned pk = (unsigned)f2bf(ax) | ((unsigned)f2bf(ay) << 16);
  *(unsigned*)(ctxbf + (size_t)b * ENCn + e0) = pk;
}

// ---------------- gates GEMM, split-K: grid (128 n-blocks, 6 K-slices) --------
__global__ __launch_bounds__(256) void k_gates_split(
    const u16* __restrict__ ctxbf, const float* __restrict__ embw,
    const int* __restrict__ caps, int t, const u16* __restrict__ hin,
    const u16* __restrict__ Wih, const u16* __restrict__ Whh,
    float* __restrict__ part) {
  int wid = threadIdx.x >> 6, lane = threadIdx.x & 63;
  int r = lane & 15, hi = lane >> 4;
  int n0 = blockIdx.x * 16;
  int sl = blockIdx.y;
  int brow = wid * 16 + r;
  f32x4 acc = {0.f, 0.f, 0.f, 0.f};
  if (sl < 4) {
    const u16* a = ctxbf + (size_t)brow * ENCn + sl * 512 + hi * 8;
    const u16* w = Wih + (size_t)(n0 + r) * 2560 + sl * 512 + hi * 8;
#pragma unroll 4
    for (int k = 0; k < 512; k += 32) acc = mfma(ld8(a + k), ld8(w + k), acc);
  } else if (sl == 4) {
    int id = caps[brow * Sn + t];
    const float* a = embw + (size_t)id * EMBn + hi * 8;
    const u16* w = Wih + (size_t)(n0 + r) * 2560 + 2048 + hi * 8;
#pragma unroll 4
    for (int k = 0; k < 512; k += 32) acc = mfma(ld8(a + k), ld8(w + k), acc);
  } else {
    const u16* a = hin + (size_t)brow * DECn + hi * 8;
    const u16* w = Whh + (size_t)(n0 + r) * 512 + hi * 8;
#pragma unroll 4
    for (int k = 0; k < 512; k += 32) acc = mfma(ld8(a + k), ld8(w + k), acc);
  }
#pragma unroll
  for (int j = 0; j < 4; j++) {
    int row = wid * 16 + hi * 4 + j;
    part[((size_t)sl * 64 + row) * 2048 + n0 + r] = acc[j];
  }
}

// ---------------- partial reduce + LSTM pointwise + dec_proj ------------------
// grid 64 blocks (one b), 512 thr (one LSTM dim / one decp col each).
__global__ __launch_bounds__(512) void k_lstm_decp(
    const float* __restrict__ part, const float* __restrict__ bih,
    const float* __restrict__ bhh, float* __restrict__ cbuf,
    u16* __restrict__ hnew, const u16* __restrict__ wdec,
    const float* __restrict__ wdecb, float* __restrict__ decp) {
  __shared__ float sh[DECn];
  int b = blockIdx.x, d = threadIdx.x;
  float g[4];
#pragma unroll
  for (int gi = 0; gi < 4; gi++) {
    int col = gi * 512 + d;
    float s = bih[col] + bhh[col];
#pragma unroll
    for (int sl = 0; sl < 6; sl++) s += part[((size_t)sl * 64 + b) * 2048 + col];
    g[gi] = s;
  }
  size_t ci = (size_t)b * DECn + d;
  float cn = sigm(g[1]) * cbuf[ci] + sigm(g[0]) * tanh_fast(g[2]);
  float hn = sigm(g[3]) * tanh_fast(cn);
  cbuf[ci] = cn;
  hnew[ci] = f2bf(hn);
  sh[d] = hn;
  __syncthreads();
  const u16* wr = wdec + (size_t)d * DECn;
  float acc = 0.f;
  for (int k = 0; k < DECn; k += 8) {
    s16x8 w8 = *(const s16x8*)(wr + k);
#pragma unroll
    for (int j = 0; j < 8; j++) acc += bf2f((u16)w8[j]) * sh[k + j];
  }
  decp[ci] = acc + wdecb[d];
}

// ---------------- deferred logits GEMM: [1280,10000] = Hall @ fcw^T + b -------
__global__ __launch_bounds__(256) void k_logits(
    const u16* __restrict__ hA, const u16* __restrict__ Wbf,
    const float* __restrict__ bias, float* __restrict__ out) {
  __shared__ u16 As[128][32];
  __shared__ u16 Bs[128][32];
  int tid = threadIdx.x;
  int wid = tid >> 6, lane = tid & 63, r = lane & 15, hi = lane >> 4;
  int wm = wid >> 1, wn = wid & 1;
  int m0 = blockIdx.y * 128, n0 = blockIdx.x * 128;
  int srow = tid >> 2, scol = (tid & 3) * 8;
  const u16* ga = hA + (size_t)(m0 + srow) * 512 + scol;
  int br1 = n0 + srow;       if (br1 > VOCABn - 1) br1 = VOCABn - 1;
  int br2 = n0 + 64 + srow;  if (br2 > VOCABn - 1) br2 = VOCABn - 1;
  const u16* gb1 = Wbf + (size_t)br1 * 512 + scol;
  const u16* gb2 = Wbf + (size_t)br2 * 512 + scol;
  u16* As1 = &As[0][0];
  u16* Bs1 = &Bs[0][0];
  f32x4 acc[4][4] = {};
  for (int k0 = 0; k0 < 512; k0 += 32) {
    GLOAD_LDS16(ga + k0,                     As1 + wid * 512);
    GLOAD_LDS16(ga + k0 + (size_t)64 * 512,  As1 + 2048 + wid * 512);
    GLOAD_LDS16(gb1 + k0,                    Bs1 + wid * 512);
    GLOAD_LDS16(gb2 + k0,                    Bs1 + 2048 + wid * 512);
    __syncthreads();
    s16x8 af[4], bfr[4];
#pragma unroll
    for (int i = 0; i < 4; i++) af[i]  = *(const s16x8*)(As1 + (wm * 64 + i * 16 + r) * 32 + hi * 8);
#pragma unroll
    for (int j = 0; j < 4; j++) bfr[j] = *(const s16x8*)(Bs1 + (wn * 64 + j * 16 + r) * 32 + hi * 8);
#pragma unroll
    for (int i = 0; i < 4; i++)
#pragma unroll
      for (int j = 0; j < 4; j++)
        acc[i][j] = mfma(af[i], bfr[j], acc[i][j]);
    __syncthreads();
  }
#pragma unroll
  for (int i = 0; i < 4; i++)
#pragma unroll
    for (int j = 0; j < 4; j++) {
      int col = n0 + wn * 64 + j * 16 + r;
      if (col < VOCABn) {
        float bb = bias[col];
#pragma unroll
        for (int q = 0; q < 4; q++) {
          int row = m0 + wm * 64 + i * 16 + hi * 4 + q;   // row = t*64 + b
          int tt = row >> 6, b = row & 63;
          out[((size_t)b * Sn + tt) * VOCABn + col] = acc[i][j][q] + bb;
        }
      }
    }
}

// ============================================================================
extern "C" void kernel_launch(void* const* d_in, const int* in_sizes, int n_in,
                              void* d_out, int out_size, void* d_ws, size_t ws_size,
                              hipStream_t stream) {
  const float* image_feat = (const float*)d_in[0];
  const int*   captions   = (const int*)d_in[1];
  const float* wenc_w = (const float*)d_in[2];
  const float* wenc_b = (const float*)d_in[3];
  const float* wdec_w = (const float*)d_in[4];
  const float* wdec_b = (const float*)d_in[5];
  const float* V_w    = (const float*)d_in[6];
  const float* V_b    = (const float*)d_in[7];
  const float* embed_w = (const float*)d_in[8];
  const float* h0_w = (const float*)d_in[9];
  const float* h0_b = (const float*)d_in[10];
  const float* c0_w = (const float*)d_in[11];
  const float* c0_b = (const float*)d_in[12];
  const float* W_ih = (const float*)d_in[13];
  const float* b_ih = (const float*)d_in[14];
  const float* W_hh = (const float*)d_in[15];
  const float* b_hh = (const float*)d_in[16];
  const float* fc_w = (const float*)d_in[17];
  const float* fc_b = (const float*)d_in[18];
  float* out = (float*)d_out;

  char* w = (char*)d_ws;
  auto alloc = [&](size_t bytes) { void* p = (void*)w; w += (bytes + 255) & ~(size_t)255; return p; };
  u16* if_bf   = (u16*)alloc(sizeof(u16) * (size_t)Bn * Pn * ENCn);
  u16* wenc_bf = (u16*)alloc(sizeof(u16) * (size_t)ATTn * ENCn);
  u16* wdec_bf = (u16*)alloc(sizeof(u16) * (size_t)ATTn * DECn);
  u16* Wih_bf  = (u16*)alloc(sizeof(u16) * (size_t)2048 * 2560);
  u16* Whh_bf  = (u16*)alloc(sizeof(u16) * (size_t)2048 * 512);
  u16* fcw_bf  = (u16*)alloc(sizeof(u16) * (size_t)VOCABn * DECn);
  u16* hall    = (u16*)alloc(sizeof(u16) * (size_t)(Sn + 1) * Bn * DECn);
  u16* ctx_bf  = (u16*)alloc(sizeof(u16) * (size_t)Bn * ENCn);
  u16* encp    = (u16*)alloc(sizeof(u16) * (size_t)Bn * Pn * ATTn);
  float* avg   = (float*)alloc(sizeof(float) * (size_t)Bn * ENCn);
  float* decp  = (float*)alloc(sizeof(float) * (size_t)Bn * ATTn);
  float* cbuf  = (float*)alloc(sizeof(float) * (size_t)Bn * DECn);
  float* part  = (float*)alloc(sizeof(float) * (size_t)6 * Bn * 2048);

  // one-time conversions
  k_cvtfeat_avg<<<dim3(2, Bn), 256, 0, stream>>>(image_feat, if_bf, avg);
  k_cvt_all<<<2048, 256, 0, stream>>>(wenc_w, wenc_bf, wdec_w, wdec_bf,
                                      W_ih, Wih_bf, W_hh, Whh_bf, fc_w, fcw_bf);
  k_encproj<<<dim3(4, 98), 256, 0, stream>>>(if_bf, wenc_bf, wenc_b, encp);
  k_h0c0<<<64, 256, 0, stream>>>(avg, h0_w, h0_b, c0_w, c0_b, hall, cbuf);
  k_lin64<u16, u16, 512><<<32, 256, 0, stream>>>(hall, wdec_bf, wdec_b, decp, 512);

  for (int t = 0; t < Sn; t++) {
    const u16* hin = hall + (size_t)t * Bn * DECn;
    u16* hnew = hall + (size_t)(t + 1) * Bn * DECn;
    k_attn_ctx<<<dim3(4, Bn), 256, 0, stream>>>(encp, decp, V_w, V_b, if_bf, ctx_bf);
    k_gates_split<<<dim3(128, 6), 256, 0, stream>>>(ctx_bf, embed_w, captions, t, hin,
                                                    Wih_bf, Whh_bf, part);
    k_lstm_decp<<<Bn, 512, 0, stream>>>(part, b_ih, b_hh, cbuf, hnew,
                                        wdec_bf, wdec_b, decp);
  }
  k_logits<<<dim3(79, 10), 256, 0, stream>>>(hall + (size_t)Bn * DECn, fcw_bf, fc_b, out);
}

// Round 6
// 1339.503 us; speedup vs baseline: 2.9384x; 1.5125x over previous
//
#include <hip/hip_runtime.h>
#include <hip/hip_bf16.h>

#define DEV static __device__ __forceinline__

typedef short s16x8 __attribute__((ext_vector_type(8)));
typedef float f32x4 __attribute__((ext_vector_type(4)));
typedef unsigned short u16;

constexpr int Bn = 64, Pn = 196, ENCn = 2048, EMBn = 512, DECn = 512, ATTn = 512;
constexpr int VOCABn = 10000, Sn = 20;

DEV u16 f2bf(float x) {
  union { float f; unsigned u; } v; v.f = x;
  unsigned r = v.u + 0x7fffu + ((v.u >> 16) & 1u);
  return (u16)(r >> 16);
}
DEV float bf2f(u16 b) {
  union { unsigned u; float f; } v; v.u = ((unsigned)b) << 16;
  return v.f;
}
DEV float sigm(float x) { return 1.f / (1.f + __expf(-x)); }
DEV float tanh_fast(float x) {
  float e = __expf(2.f * x);
  return 1.f - 2.f / (e + 1.f);
}

DEV s16x8 ld8(const u16* p) { return *reinterpret_cast<const s16x8*>(p); }
DEV s16x8 ld8(const float* p) {
  s16x8 r;
#pragma unroll
  for (int j = 0; j < 8; j++) r[j] = (short)f2bf(p[j]);
  return r;
}
DEV f32x4 mfma(s16x8 a, s16x8 b, f32x4 c) {
  return __builtin_amdgcn_mfma_f32_16x16x32_bf16(a, b, c, 0, 0, 0);
}

#define GLOAD_LDS16(gsrc, ldst)                                                \
  __builtin_amdgcn_global_load_lds(                                            \
      (const __attribute__((address_space(1))) void*)(gsrc),                   \
      (__attribute__((address_space(3))) void*)(ldst), 16, 0, 0)

// ---------------- all weight conversions f32 -> bf16 in ONE launch ------------
__global__ void k_cvt_all(const float* __restrict__ s0, u16* __restrict__ d0,
                          const float* __restrict__ s1, u16* __restrict__ d1,
                          const float* __restrict__ s2, u16* __restrict__ d2,
                          const float* __restrict__ s3, u16* __restrict__ d3,
                          const float* __restrict__ s4, u16* __restrict__ d4) {
  int gid = blockIdx.x * 256 + threadIdx.x, stride = gridDim.x * 256;
  auto run = [&](const float* __restrict__ s, u16* __restrict__ d, int n8) {
    for (int i = gid; i < n8; i += stride) {
      const float4* sp = (const float4*)(s + (size_t)i * 8);
      float4 a = sp[0], b = sp[1];
      s16x8 o;
      o[0] = (short)f2bf(a.x); o[1] = (short)f2bf(a.y);
      o[2] = (short)f2bf(a.z); o[3] = (short)f2bf(a.w);
      o[4] = (short)f2bf(b.x); o[5] = (short)f2bf(b.y);
      o[6] = (short)f2bf(b.z); o[7] = (short)f2bf(b.w);
      *(s16x8*)(d + (size_t)i * 8) = o;
    }
  };
  run(s0, d0, 131072);   // wenc 512*2048
  run(s1, d1, 32768);    // wdec 512*512
  run(s2, d2, 655360);   // W_ih 2048*2560
  run(s3, d3, 131072);   // W_hh 2048*512
  run(s4, d4, 640000);   // fc_w 10000*512
}

// ---------------- image_feat cvt + partial mean over 28-row p-chunks ----------
// grid (7, 64) = 448 blocks. thread owns 8 dims; 28 rows each; coalesced 8KB rows.
__global__ __launch_bounds__(256) void k_cvtfeat_part(
    const float* __restrict__ feat, u16* __restrict__ featbf,
    float* __restrict__ pavg) {
  int b = blockIdx.y, px = blockIdx.x;
  int d8 = threadIdx.x * 8;
  const float* p = feat + ((size_t)b * Pn + px * 28) * ENCn + d8;
  u16* q = featbf + ((size_t)b * Pn + px * 28) * ENCn + d8;
  float acc[8] = {};
  for (int k = 0; k < 28; k++) {
    float4 v0 = *(const float4*)(p + (size_t)k * ENCn);
    float4 v1 = *(const float4*)(p + (size_t)k * ENCn + 4);
    acc[0] += v0.x; acc[1] += v0.y; acc[2] += v0.z; acc[3] += v0.w;
    acc[4] += v1.x; acc[5] += v1.y; acc[6] += v1.z; acc[7] += v1.w;
    s16x8 o;
    o[0] = (short)f2bf(v0.x); o[1] = (short)f2bf(v0.y);
    o[2] = (short)f2bf(v0.z); o[3] = (short)f2bf(v0.w);
    o[4] = (short)f2bf(v1.x); o[5] = (short)f2bf(v1.y);
    o[6] = (short)f2bf(v1.z); o[7] = (short)f2bf(v1.w);
    *(s16x8*)(q + (size_t)k * ENCn) = o;
  }
  float* pp = pavg + ((size_t)px * Bn + b) * ENCn + d8;
  *(f32x4*)pp = f32x4{acc[0], acc[1], acc[2], acc[3]};
  *(f32x4*)(pp + 4) = f32x4{acc[4], acc[5], acc[6], acc[7]};
}

// ---------------- final mean reduce: avg = sum(pavg[0..6]) / 196 --------------
__global__ __launch_bounds__(256) void k_avg_final(
    const float* __restrict__ pavg, float* __restrict__ avg) {
  int idx = blockIdx.x * 256 + threadIdx.x;   // over 32768 float4s
  int b = idx >> 9, e4 = (idx & 511) * 4;
  float4 s = {0.f, 0.f, 0.f, 0.f};
#pragma unroll
  for (int px = 0; px < 7; px++) {
    float4 v = *(const float4*)(pavg + ((size_t)px * Bn + b) * ENCn + e4);
    s.x += v.x; s.y += v.y; s.z += v.z; s.w += v.w;
  }
  float4 o = { s.x * (1.f/196.f), s.y * (1.f/196.f), s.z * (1.f/196.f), s.w * (1.f/196.f) };
  *(float4*)(avg + (size_t)b * ENCn + e4) = o;
}

// ---------------- h0 + c0 in one launch (64 blocks) ---------------------------
__global__ __launch_bounds__(256) void k_h0c0(
    const float* __restrict__ avg,
    const float* __restrict__ h0w, const float* __restrict__ h0b,
    const float* __restrict__ c0w, const float* __restrict__ c0b,
    u16* __restrict__ h0out, float* __restrict__ c0out) {
  int wid = threadIdx.x >> 6, lane = threadIdx.x & 63;
  int r = lane & 15, hi = lane >> 4;
  bool isC = blockIdx.x >= 32;
  int n0 = ((int)blockIdx.x & 31) * 16;
  const float* W = (isC ? c0w : h0w) + (size_t)(n0 + r) * ENCn + hi * 8;
  const float* ap = avg + (size_t)(wid * 16 + r) * ENCn + hi * 8;
  f32x4 acc = {0.f, 0.f, 0.f, 0.f};
  for (int k = 0; k < ENCn; k += 32) acc = mfma(ld8(ap + k), ld8(W + k), acc);
  int col = n0 + r;
  float bb = (isC ? c0b : h0b)[col];
#pragma unroll
  for (int j = 0; j < 4; j++) {
    int row = wid * 16 + hi * 4 + j;
    float v = fmaxf(acc[j] + bb, 0.f);
    if (isC) c0out[(size_t)row * DECn + col] = v;
    else     h0out[(size_t)row * DECn + col] = f2bf(v);
  }
}

// ---------------- generic skinny GEMM (used once for decp0) -------------------
template<typename TA, typename TW, int K>
__global__ __launch_bounds__(256) void k_lin64(
    const TA* __restrict__ A, const TW* __restrict__ W,
    const float* __restrict__ bias1, float* __restrict__ outF, size_t ldo) {
  int wid = threadIdx.x >> 6, lane = threadIdx.x & 63;
  int r = lane & 15, hi = lane >> 4;
  int n0 = blockIdx.x * 16;
  const TA* ap = A + (size_t)(wid * 16 + r) * K + hi * 8;
  const TW* wp = W + (size_t)(n0 + r) * K + hi * 8;
  f32x4 acc = {0.f, 0.f, 0.f, 0.f};
  for (int k = 0; k < K; k += 32) acc = mfma(ld8(ap + k), ld8(wp + k), acc);
  int col = n0 + r;
  float bb = bias1[col];
#pragma unroll
  for (int j = 0; j < 4; j++) {
    int row = wid * 16 + hi * 4 + j;
    outF[(size_t)row * ldo + col] = acc[j] + bb;
  }
}

// ---------------- enc_proj: 128x128 tile, BK=32, global_load_lds, bf16 out ----
__global__ __launch_bounds__(256) void k_encproj(
    const u16* __restrict__ Abf, const u16* __restrict__ Wbf,
    const float* __restrict__ bias, u16* __restrict__ out) {
  __shared__ u16 As[128][32];
  __shared__ u16 Bs[128][32];
  int tid = threadIdx.x;
  int wid = tid >> 6, lane = tid & 63, r = lane & 15, hi = lane >> 4;
  int wm = wid >> 1, wn = wid & 1;
  int m0 = blockIdx.y * 128, n0 = blockIdx.x * 128;
  int srow = tid >> 2, scol = (tid & 3) * 8;
  const u16* ga = Abf + (size_t)(m0 + srow) * ENCn + scol;
  const u16* gb = Wbf + (size_t)(n0 + srow) * ENCn + scol;
  u16* As1 = &As[0][0];
  u16* Bs1 = &Bs[0][0];
  f32x4 acc[4][4] = {};
  for (int k0 = 0; k0 < ENCn; k0 += 32) {
    GLOAD_LDS16(ga + k0,                      As1 + wid * 512);
    GLOAD_LDS16(ga + k0 + (size_t)64 * ENCn,  As1 + 2048 + wid * 512);
    GLOAD_LDS16(gb + k0,                      Bs1 + wid * 512);
    GLOAD_LDS16(gb + k0 + (size_t)64 * ENCn,  Bs1 + 2048 + wid * 512);
    __syncthreads();
    s16x8 af[4], bfr[4];
#pragma unroll
    for (int i = 0; i < 4; i++) af[i]  = *(const s16x8*)(As1 + (wm * 64 + i * 16 + r) * 32 + hi * 8);
#pragma unroll
    for (int j = 0; j < 4; j++) bfr[j] = *(const s16x8*)(Bs1 + (wn * 64 + j * 16 + r) * 32 + hi * 8);
#pragma unroll
    for (int i = 0; i < 4; i++)
#pragma unroll
      for (int j = 0; j < 4; j++)
        acc[i][j] = mfma(af[i], bfr[j], acc[i][j]);
    __syncthreads();
  }
#pragma unroll
  for (int i = 0; i < 4; i++)
#pragma unroll
    for (int j = 0; j < 4; j++) {
      int col = n0 + wn * 64 + j * 16 + r;
      float bb = bias[col];
#pragma unroll
      for (int q = 0; q < 4; q++) {
        int row = m0 + wm * 64 + i * 16 + hi * 4 + q;
        out[(size_t)row * 512 + col] = f2bf(acc[i][j][q] + bb);
      }
    }
}

// ---------------- attention scores: wave per (b,p); grid (49, 64) --------------
__global__ __launch_bounds__(256) void k_attn(
    const u16* __restrict__ encp, const float* __restrict__ decp,
    const float* __restrict__ Vw, const float* __restrict__ Vb,
    float* __restrict__ e) {
  int wid = threadIdx.x >> 6, lane = threadIdx.x & 63;
  int p = blockIdx.x * 4 + wid;
  int b = blockIdx.y;
  const float* dp = decp + (size_t)b * ATTn + lane * 8;
  float4 dv0 = *(const float4*)dp, dv1 = *(const float4*)(dp + 4);
  float4 vv0 = *(const float4*)(Vw + lane * 8), vv1 = *(const float4*)(Vw + lane * 8 + 4);
  s16x8 ev = *(const s16x8*)(encp + (((size_t)(b * Pn + p)) << 9) + lane * 8);
  float s = 0.f;
  s += vv0.x * tanh_fast(bf2f((u16)ev[0]) + dv0.x);
  s += vv0.y * tanh_fast(bf2f((u16)ev[1]) + dv0.y);
  s += vv0.z * tanh_fast(bf2f((u16)ev[2]) + dv0.z);
  s += vv0.w * tanh_fast(bf2f((u16)ev[3]) + dv0.w);
  s += vv1.x * tanh_fast(bf2f((u16)ev[4]) + dv1.x);
  s += vv1.y * tanh_fast(bf2f((u16)ev[5]) + dv1.y);
  s += vv1.z * tanh_fast(bf2f((u16)ev[6]) + dv1.z);
  s += vv1.w * tanh_fast(bf2f((u16)ev[7]) + dv1.w);
  for (int m = 32; m; m >>= 1) s += __shfl_xor(s, m);
  if (lane == 0) e[(size_t)b * Pn + p] = s + Vb[0];
}

// ---------------- softmax + ctx chunk, p-parallel ------------------------------
// grid (4, 64). 256 thr = 4 p-groups x 64 dim-threads; thread owns 8 dims,
// 49 p-iterations of 16B loads; LDS partial reduce across groups.
__global__ __launch_bounds__(256) void k_ctx(
    const float* __restrict__ e, const u16* __restrict__ featbf,
    u16* __restrict__ ctxbf) {
  __shared__ float sw[Pn];
  __shared__ float red[256];
  __shared__ float pacc[4 * 512];
  int b = blockIdx.y, chunk = blockIdx.x, tid = threadIdx.x;
  // softmax over 196 (block-wide recompute)
  float ev = (tid < Pn) ? e[(size_t)b * Pn + tid] : -3.0e38f;
  red[tid] = ev; __syncthreads();
  for (int s = 128; s > 0; s >>= 1) { if (tid < s) red[tid] = fmaxf(red[tid], red[tid + s]); __syncthreads(); }
  float m = red[0]; __syncthreads();
  float ex = (tid < Pn) ? __expf(ev - m) : 0.f;
  red[tid] = ex; __syncthreads();
  for (int s = 128; s > 0; s >>= 1) { if (tid < s) red[tid] += red[tid + s]; __syncthreads(); }
  float inv = 1.f / red[0];
  if (tid < Pn) sw[tid] = ex * inv;
  __syncthreads();
  // weighted sum: group g handles p = g, g+4, ... ; thread owns 8 dims
  int g = tid >> 6, t64 = tid & 63;
  int dloc = t64 * 8;
  const u16* fp = featbf + (size_t)b * Pn * ENCn + chunk * 512 + dloc;
  float acc[8] = {};
  for (int p = g; p < Pn; p += 4) {
    float w = sw[p];
    s16x8 v = *(const s16x8*)(fp + (size_t)p * ENCn);
#pragma unroll
    for (int j = 0; j < 8; j++) acc[j] += w * bf2f((u16)v[j]);
  }
#pragma unroll
  for (int j = 0; j < 8; j++) pacc[g * 512 + dloc + j] = acc[j];
  __syncthreads();
  // final: thread handles 2 dims
  int dd = tid * 2;
  float a0 = pacc[dd]       + pacc[512 + dd]     + pacc[1024 + dd]     + pacc[1536 + dd];
  float a1 = pacc[dd + 1]   + pacc[512 + dd + 1] + pacc[1024 + dd + 1] + pacc[1536 + dd + 1];
  unsigned pk = (unsigned)f2bf(a0) | ((unsigned)f2bf(a1) << 16);
  *(unsigned*)(ctxbf + (size_t)b * ENCn + chunk * 512 + dd) = pk;
}

// ---------------- gates GEMM, split-K: grid (128 n-blocks, 6 K-slices) --------
__global__ __launch_bounds__(256) void k_gates_split(
    const u16* __restrict__ ctxbf, const float* __restrict__ embw,
    const int* __restrict__ caps, int t, const u16* __restrict__ hin,
    const u16* __restrict__ Wih, const u16* __restrict__ Whh,
    float* __restrict__ part) {
  int wid = threadIdx.x >> 6, lane = threadIdx.x & 63;
  int r = lane & 15, hi = lane >> 4;
  int n0 = blockIdx.x * 16;
  int sl = blockIdx.y;
  int brow = wid * 16 + r;
  f32x4 acc = {0.f, 0.f, 0.f, 0.f};
  if (sl < 4) {
    const u16* a = ctxbf + (size_t)brow * ENCn + sl * 512 + hi * 8;
    const u16* w = Wih + (size_t)(n0 + r) * 2560 + sl * 512 + hi * 8;
#pragma unroll 4
    for (int k = 0; k < 512; k += 32) acc = mfma(ld8(a + k), ld8(w + k), acc);
  } else if (sl == 4) {
    int id = caps[brow * Sn + t];
    const float* a = embw + (size_t)id * EMBn + hi * 8;
    const u16* w = Wih + (size_t)(n0 + r) * 2560 + 2048 + hi * 8;
#pragma unroll 4
    for (int k = 0; k < 512; k += 32) acc = mfma(ld8(a + k), ld8(w + k), acc);
  } else {
    const u16* a = hin + (size_t)brow * DECn + hi * 8;
    const u16* w = Whh + (size_t)(n0 + r) * 512 + hi * 8;
#pragma unroll 4
    for (int k = 0; k < 512; k += 32) acc = mfma(ld8(a + k), ld8(w + k), acc);
  }
#pragma unroll
  for (int j = 0; j < 4; j++) {
    int row = wid * 16 + hi * 4 + j;
    part[((size_t)sl * 64 + row) * 2048 + n0 + r] = acc[j];
  }
}

// ---------------- partial reduce + LSTM pointwise + dec_proj ------------------
// grid 64 blocks (one b), 512 thr (one LSTM dim / one decp col each).
__global__ __launch_bounds__(512) void k_lstm_decp(
    const float* __restrict__ part, const float* __restrict__ bih,
    const float* __restrict__ bhh, float* __restrict__ cbuf,
    u16* __restrict__ hnew, const u16* __restrict__ wdec,
    const float* __restrict__ wdecb, float* __restrict__ decp) {
  __shared__ float sh[DECn];
  int b = blockIdx.x, d = threadIdx.x;
  float g[4];
#pragma unroll
  for (int gi = 0; gi < 4; gi++) {
    int col = gi * 512 + d;
    float s = bih[col] + bhh[col];
#pragma unroll
    for (int sl = 0; sl < 6; sl++) s += part[((size_t)sl * 64 + b) * 2048 + col];
    g[gi] = s;
  }
  size_t ci = (size_t)b * DECn + d;
  float cn = sigm(g[1]) * cbuf[ci] + sigm(g[0]) * tanh_fast(g[2]);
  float hn = sigm(g[3]) * tanh_fast(cn);
  cbuf[ci] = cn;
  hnew[ci] = f2bf(hn);
  sh[d] = hn;
  __syncthreads();
  const u16* wr = wdec + (size_t)d * DECn;
  float acc = 0.f;
  for (int k = 0; k < DECn; k += 8) {
    s16x8 w8 = *(const s16x8*)(wr + k);
#pragma unroll
    for (int j = 0; j < 8; j++) acc += bf2f((u16)w8[j]) * sh[k + j];
  }
  decp[ci] = acc + wdecb[d];
}

// ---------------- deferred logits GEMM: [1280,10000] = Hall @ fcw^T + b -------
__global__ __launch_bounds__(256) void k_logits(
    const u16* __restrict__ hA, const u16* __restrict__ Wbf,
    const float* __restrict__ bias, float* __restrict__ out) {
  __shared__ u16 As[128][32];
  __shared__ u16 Bs[128][32];
  int tid = threadIdx.x;
  int wid = tid >> 6, lane = tid & 63, r = lane & 15, hi = lane >> 4;
  int wm = wid >> 1, wn = wid & 1;
  int m0 = blockIdx.y * 128, n0 = blockIdx.x * 128;
  int srow = tid >> 2, scol = (tid & 3) * 8;
  const u16* ga = hA + (size_t)(m0 + srow) * 512 + scol;
  int br1 = n0 + srow;       if (br1 > VOCABn - 1) br1 = VOCABn - 1;
  int br2 = n0 + 64 + srow;  if (br2 > VOCABn - 1) br2 = VOCABn - 1;
  const u16* gb1 = Wbf + (size_t)br1 * 512 + scol;
  const u16* gb2 = Wbf + (size_t)br2 * 512 + scol;
  u16* As1 = &As[0][0];
  u16* Bs1 = &Bs[0][0];
  f32x4 acc[4][4] = {};
  for (int k0 = 0; k0 < 512; k0 += 32) {
    GLOAD_LDS16(ga + k0,                     As1 + wid * 512);
    GLOAD_LDS16(ga + k0 + (size_t)64 * 512,  As1 + 2048 + wid * 512);
    GLOAD_LDS16(gb1 + k0,                    Bs1 + wid * 512);
    GLOAD_LDS16(gb2 + k0,                    Bs1 + 2048 + wid * 512);
    __syncthreads();
    s16x8 af[4], bfr[4];
#pragma unroll
    for (int i = 0; i < 4; i++) af[i]  = *(const s16x8*)(As1 + (wm * 64 + i * 16 + r) * 32 + hi * 8);
#pragma unroll
    for (int j = 0; j < 4; j++) bfr[j] = *(const s16x8*)(Bs1 + (wn * 64 + j * 16 + r) * 32 + hi * 8);
#pragma unroll
    for (int i = 0; i < 4; i++)
#pragma unroll
      for (int j = 0; j < 4; j++)
        acc[i][j] = mfma(af[i], bfr[j], acc[i][j]);
    __syncthreads();
  }
#pragma unroll
  for (int i = 0; i < 4; i++)
#pragma unroll
    for (int j = 0; j < 4; j++) {
      int col = n0 + wn * 64 + j * 16 + r;
      if (col < VOCABn) {
        float bb = bias[col];
#pragma unroll
        for (int q = 0; q < 4; q++) {
          int row = m0 + wm * 64 + i * 16 + hi * 4 + q;   // row = t*64 + b
          int tt = row >> 6, b = row & 63;
          out[((size_t)b * Sn + tt) * VOCABn + col] = acc[i][j][q] + bb;
        }
      }
    }
}

// ============================================================================
extern "C" void kernel_launch(void* const* d_in, const int* in_sizes, int n_in,
                              void* d_out, int out_size, void* d_ws, size_t ws_size,
                              hipStream_t stream) {
  const float* image_feat = (const float*)d_in[0];
  const int*   captions   = (const int*)d_in[1];
  const float* wenc_w = (const float*)d_in[2];
  const float* wenc_b = (const float*)d_in[3];
  const float* wdec_w = (const float*)d_in[4];
  const float* wdec_b = (const float*)d_in[5];
  const float* V_w    = (const float*)d_in[6];
  const float* V_b    = (const float*)d_in[7];
  const float* embed_w = (const float*)d_in[8];
  const float* h0_w = (const float*)d_in[9];
  const float* h0_b = (const float*)d_in[10];
  const float* c0_w = (const float*)d_in[11];
  const float* c0_b = (const float*)d_in[12];
  const float* W_ih = (const float*)d_in[13];
  const float* b_ih = (const float*)d_in[14];
  const float* W_hh = (const float*)d_in[15];
  const float* b_hh = (const float*)d_in[16];
  const float* fc_w = (const float*)d_in[17];
  const float* fc_b = (const float*)d_in[18];
  float* out = (float*)d_out;

  char* w = (char*)d_ws;
  auto alloc = [&](size_t bytes) { void* p = (void*)w; w += (bytes + 255) & ~(size_t)255; return p; };
  u16* if_bf   = (u16*)alloc(sizeof(u16) * (size_t)Bn * Pn * ENCn);
  u16* wenc_bf = (u16*)alloc(sizeof(u16) * (size_t)ATTn * ENCn);
  u16* wdec_bf = (u16*)alloc(sizeof(u16) * (size_t)ATTn * DECn);
  u16* Wih_bf  = (u16*)alloc(sizeof(u16) * (size_t)2048 * 2560);
  u16* Whh_bf  = (u16*)alloc(sizeof(u16) * (size_t)2048 * 512);
  u16* fcw_bf  = (u16*)alloc(sizeof(u16) * (size_t)VOCABn * DECn);
  u16* hall    = (u16*)alloc(sizeof(u16) * (size_t)(Sn + 1) * Bn * DECn);
  u16* ctx_bf  = (u16*)alloc(sizeof(u16) * (size_t)Bn * ENCn);
  u16* encp    = (u16*)alloc(sizeof(u16) * (size_t)Bn * Pn * ATTn);
  float* avg   = (float*)alloc(sizeof(float) * (size_t)Bn * ENCn);
  float* pavg  = (float*)alloc(sizeof(float) * (size_t)7 * Bn * ENCn);
  float* decp  = (float*)alloc(sizeof(float) * (size_t)Bn * ATTn);
  float* e_s   = (float*)alloc(sizeof(float) * (size_t)Bn * Pn);
  float* cbuf  = (float*)alloc(sizeof(float) * (size_t)Bn * DECn);
  float* part  = (float*)alloc(sizeof(float) * (size_t)6 * Bn * 2048);

  // one-time conversions and init
  k_cvtfeat_part<<<dim3(7, Bn), 256, 0, stream>>>(image_feat, if_bf, pavg);
  k_avg_final<<<128, 256, 0, stream>>>(pavg, avg);
  k_cvt_all<<<2048, 256, 0, stream>>>(wenc_w, wenc_bf, wdec_w, wdec_bf,
                                      W_ih, Wih_bf, W_hh, Whh_bf, fc_w, fcw_bf);
  k_encproj<<<dim3(4, 98), 256, 0, stream>>>(if_bf, wenc_bf, wenc_b, encp);
  k_h0c0<<<64, 256, 0, stream>>>(avg, h0_w, h0_b, c0_w, c0_b, hall, cbuf);
  k_lin64<u16, u16, 512><<<32, 256, 0, stream>>>(hall, wdec_bf, wdec_b, decp, 512);

  for (int t = 0; t < Sn; t++) {
    const u16* hin = hall + (size_t)t * Bn * DECn;
    u16* hnew = hall + (size_t)(t + 1) * Bn * DECn;
    k_attn<<<dim3(49, Bn), 256, 0, stream>>>(encp, decp, V_w, V_b, e_s);
    k_ctx<<<dim3(4, Bn), 256, 0, stream>>>(e_s, if_bf, ctx_bf);
    k_gates_split<<<dim3(128, 6), 256, 0, stream>>>(ctx_bf, embed_w, captions, t, hin,
                                                    Wih_bf, Whh_bf, part);
    k_lstm_decp<<<Bn, 512, 0, stream>>>(part, b_ih, b_hh, cbuf, hnew,
                                        wdec_bf, wdec_b, decp);
  }
  k_logits<<<dim3(79, 10), 256, 0, stream>>>(hall + (size_t)Bn * DECn, fcw_bf, fc_b, out);
}